// Round 5
// baseline (693.754 us; speedup 1.0000x reference)
//
#include <hip/hip_runtime.h>
#include <math.h>

#define NE 8
#define HD 1024
#define FD 2048
#define NT 4096
#define NSLOT (NT * 2)

typedef __attribute__((ext_vector_type(8))) _Float16 half8;
typedef __attribute__((ext_vector_type(4))) _Float16 half4f;
typedef __attribute__((ext_vector_type(4))) float floatx4;

// async global->LDS, 16B per lane. LDS dest is wave-uniform base + lane*16.
__device__ __forceinline__ void gload_lds(const _Float16* g, _Float16* l) {
  __builtin_amdgcn_global_load_lds(
      (const __attribute__((address_space(1))) unsigned int*)g,
      (__attribute__((address_space(3))) unsigned int*)l, 16, 0, 0);
}

template <int N>
__device__ __forceinline__ void waitcnt_vm() {
  if constexpr (N == 0) asm volatile("s_waitcnt vmcnt(0)" ::: "memory");
  else if constexpr (N == 4) asm volatile("s_waitcnt vmcnt(4)" ::: "memory");
  else static_assert(N < 0, "unsupported vmcnt");
}

// ---------------- conversions ----------------
__global__ void cvt_x_kernel(const float* __restrict__ x, _Float16* __restrict__ xh) {
  size_t i = (size_t)(blockIdx.x * 256 + threadIdx.x) * 8;
  float4 f0 = *(const float4*)(x + i);
  float4 f1 = *(const float4*)(x + i + 4);
  union { _Float16 h[8]; uint4 v; } u;
  u.h[0] = (_Float16)f0.x; u.h[1] = (_Float16)f0.y;
  u.h[2] = (_Float16)f0.z; u.h[3] = (_Float16)f0.w;
  u.h[4] = (_Float16)f1.x; u.h[5] = (_Float16)f1.y;
  u.h[6] = (_Float16)f1.z; u.h[7] = (_Float16)f1.w;
  *(uint4*)(xh + i) = u.v;
}

// in: [E][R][C] fp32 -> out: [E][C][R] fp16
__global__ void transpose_cvt(const float* __restrict__ in, _Float16* __restrict__ outp,
                              int R, int C) {
  __shared__ float t[32][33];
  int e = blockIdx.z;
  int r0 = blockIdx.x * 32, c0 = blockIdx.y * 32;
  int tx = threadIdx.x, ty = threadIdx.y;
  const float* src = in + (size_t)e * R * C;
#pragma unroll
  for (int i = 0; i < 4; i++)
    t[ty + 8 * i][tx] = src[(size_t)(r0 + ty + 8 * i) * C + c0 + tx];
  __syncthreads();
  _Float16* dst = outp + (size_t)e * R * C;
#pragma unroll
  for (int i = 0; i < 4; i++) {
    int c = c0 + ty + 8 * i;
    dst[(size_t)c * R + r0 + tx] = (_Float16)t[tx][ty + 8 * i];
  }
}

// ---------------- router ----------------
__global__ __launch_bounds__(256) void router_probs_kernel(
    const float* __restrict__ x, const float* __restrict__ rw,
    float* __restrict__ probs, int* __restrict__ sel_e, float* __restrict__ sel_w) {
  int n = blockIdx.x * 4 + (threadIdx.x >> 6);
  int lane = threadIdx.x & 63;
  const float* xr = x + (size_t)n * HD;
  float xv[16];
#pragma unroll
  for (int t = 0; t < 16; t++) xv[t] = xr[lane + 64 * t];
  float logits[NE];
#pragma unroll
  for (int e = 0; e < NE; e++) {
    const float* w = rw + (size_t)e * HD;
    float acc = 0.f;
#pragma unroll
    for (int t = 0; t < 16; t++) acc += xv[t] * w[lane + 64 * t];
    for (int off = 32; off > 0; off >>= 1) acc += __shfl_down(acc, off);
    logits[e] = acc;
  }
  if (lane == 0) {
    float mx = logits[0];
#pragma unroll
    for (int e = 1; e < NE; e++) mx = fmaxf(mx, logits[e]);
    float p[NE]; float s = 0.f;
#pragma unroll
    for (int e = 0; e < NE; e++) { p[e] = expf(logits[e] - mx); s += p[e]; }
    float inv = 1.f / s;
#pragma unroll
    for (int e = 0; e < NE; e++) { p[e] *= inv; probs[n * NE + e] = p[e]; }
    int i1 = 0;
#pragma unroll
    for (int e = 1; e < NE; e++) if (p[e] > p[i1]) i1 = e;
    int i2 = -1; float p2 = -1.f;
#pragma unroll
    for (int e = 0; e < NE; e++) {
      if (e == i1) continue;
      if (p[e] > p2) { p2 = p[e]; i2 = e; }
    }
    float wn = 1.f / (p[i1] + p[i2]);
    sel_e[n * 2 + 0] = i1; sel_w[n * 2 + 0] = p[i1] * wn;
    sel_e[n * 2 + 1] = i2; sel_w[n * 2 + 1] = p[i2] * wn;
  }
}

__global__ __launch_bounds__(1024) void router_reduce_kernel(
    const float* __restrict__ probs, const int* __restrict__ sel_e,
    int* __restrict__ counts, int* __restrict__ offs, int* __restrict__ cursor,
    float* __restrict__ aux_out) {
  int t = threadIdx.x;
  int lane = t & 63, wave = t >> 6;
  float ps[NE];
  int cn[NE];
#pragma unroll
  for (int e = 0; e < NE; e++) { ps[e] = 0.f; cn[e] = 0; }
  for (int r = t; r < NT; r += 1024) {
    const float* pr = probs + (size_t)r * NE;
#pragma unroll
    for (int e = 0; e < NE; e++) ps[e] += pr[e];
  }
  for (int i = t; i < NSLOT; i += 1024) {
    int e = sel_e[i];
#pragma unroll
    for (int j = 0; j < NE; j++) cn[j] += (e == j) ? 1 : 0;
  }
  for (int off = 32; off > 0; off >>= 1) {
#pragma unroll
    for (int e = 0; e < NE; e++) {
      ps[e] += __shfl_down(ps[e], off);
      cn[e] += __shfl_down(cn[e], off);
    }
  }
  __shared__ float sps[16][NE];
  __shared__ int scn[16][NE];
  if (lane == 0) {
#pragma unroll
    for (int e = 0; e < NE; e++) { sps[wave][e] = ps[e]; scn[wave][e] = cn[e]; }
  }
  __syncthreads();
  if (t == 0) {
    float tot_p[NE]; int tot_c[NE];
#pragma unroll
    for (int e = 0; e < NE; e++) { tot_p[e] = 0.f; tot_c[e] = 0; }
    for (int w = 0; w < 16; w++)
#pragma unroll
      for (int e = 0; e < NE; e++) { tot_p[e] += sps[w][e]; tot_c[e] += scn[w][e]; }
    int o = 0;
    float aux = 0.f;
    for (int e = 0; e < NE; e++) {
      counts[e] = tot_c[e];
      offs[e] = o; o += tot_c[e];
      cursor[e] = 0;
      aux += ((float)tot_c[e] / (float)NSLOT) * (tot_p[e] / (float)NT);
    }
    aux_out[0] = (float)NE * aux;
  }
}

__global__ __launch_bounds__(256) void build_gather(
    const int* __restrict__ sel_e, const float* __restrict__ sel_w,
    const int* __restrict__ offs, int* __restrict__ cursor,
    int* __restrict__ gtok, float* __restrict__ gw, int* __restrict__ srow) {
  __shared__ int lh[NE], lbase[NE];
  int t = threadIdx.x;
  int i = blockIdx.x * 256 + t;
  if (t < NE) lh[t] = 0;
  __syncthreads();
  int e = sel_e[i];
  int lrank = atomicAdd(&lh[e], 1);
  __syncthreads();
  if (t < NE) lbase[t] = atomicAdd(&cursor[t], lh[t]);
  __syncthreads();
  int row = offs[e] + lbase[e] + lrank;
  gtok[row] = i >> 1;
  gw[row] = sel_w[i];
  srow[i] = row;
}

// ---------------- grouped GEMM: ring-3 async, chunk-major LDS windows ----------
// BM=BN=128, BK=32. LDS per stage: A = 8 windows of 16 rows, each window stored
// [chunk(4)][row(16)][16B] — exactly the DMA's lane order when lane i fetches
// global (row=i&15, kchunk=i>>4). Fragment read addr = win*512 + g*128 + fr*8
// halfs -> bank = (fr*4)%32 per 16-lane phase = conflict-free (max 2-way).
// Ring-3: issue stage kt+1, s_waitcnt vmcnt(4) drains stage kt only, raw
// s_barrier, compute. WAR-safe: slot (kt+1)%3 last read in compute(kt-2),
// finished before every wave's barrier(kt-1).
// SPLIT: blockIdx.z = e*2 + khalf; K-range = khalf*KLEN of KSTRIDE; fp16
// partial outputs to D0/D1 (summed in combine).
template <int KLEN, int KSTRIDE, int NDIM, bool IS_UP, bool SPLIT>
__global__ __launch_bounds__(256, 3) void moe_gemm4(
    const _Float16* __restrict__ Abase, const _Float16* __restrict__ Bt,
    const int* __restrict__ counts, const int* __restrict__ offs,
    const int* __restrict__ gtok, const float* __restrict__ gw,
    _Float16* __restrict__ Hout, _Float16* __restrict__ D0,
    _Float16* __restrict__ D1) {
  constexpr int BK = 32;
  constexpr int SSTR = 8192;  // halfs per stage: (128+128)*32
  constexpr int TK = KLEN / BK;

  int zz = blockIdx.z;
  int e = SPLIT ? (zz >> 1) : zz;
  int khalf = SPLIT ? (zz & 1) : 0;
  int k0base = khalf * KLEN;
  int cnt = counts[e];
  int m0 = blockIdx.x * 128;
  if (m0 >= cnt) return;
  int n0 = blockIdx.y * 128;
  int off = offs[e];

  __shared__ __align__(16) _Float16 sm[3 * SSTR];  // 48 KB

  int tid = threadIdx.x;
  int lane = tid & 63, wave = tid >> 6;
  int wm = (wave >> 1) * 64, wn = (wave & 1) * 64;

  // staging: wave stages A windows {2w,2w+1} and B windows {2w,2w+1}
  int fr16 = lane & 15, ch = lane >> 4;  // lane -> (row in window, k-chunk)
  const _Float16* gA[2];
  const _Float16* gB[2];
  int lAo[2], lBo[2];
#pragma unroll
  for (int j = 0; j < 2; j++) {
    int r = (wave * 2 + j) * 16 + fr16;
    int am = m0 + r;
    if (am > cnt - 1) am = cnt - 1;  // clamp tail (masked at epilogue)
    const _Float16* base = IS_UP ? Abase + (size_t)gtok[off + am] * KSTRIDE
                                 : Abase + (size_t)(off + am) * KSTRIDE;
    gA[j] = base + k0base + ch * 8;
    lAo[j] = (wave * 2 + j) * 512;
    gB[j] = Bt + ((size_t)e * NDIM + n0 + r) * KSTRIDE + k0base + ch * 8;
    lBo[j] = 4096 + (wave * 2 + j) * 512;
  }

  floatx4 acc[4][4];
#pragma unroll
  for (int i = 0; i < 4; i++)
#pragma unroll
    for (int j = 0; j < 4; j++) acc[i][j] = (floatx4){0.f, 0.f, 0.f, 0.f};

  int fr = lane & 15, g = lane >> 4;
  int aoff[4], boff[4];
#pragma unroll
  for (int t = 0; t < 4; t++) {
    aoff[t] = (wm / 16 + t) * 512 + g * 128 + fr * 8;
    boff[t] = 4096 + (wn / 16 + t) * 512 + g * 128 + fr * 8;
  }

  int sw = 0;  // ring write index
  auto issue = [&]() {
    _Float16* sb = sm + sw * SSTR;
#pragma unroll
    for (int j = 0; j < 2; j++) { gload_lds(gA[j], sb + lAo[j]); gA[j] += BK; }
#pragma unroll
    for (int j = 0; j < 2; j++) { gload_lds(gB[j], sb + lBo[j]); gB[j] += BK; }
    sw = (sw == 2) ? 0 : sw + 1;
  };
  issue();  // stage 0

  int cur = 0;
  for (int kt = 0; kt < TK; kt++) {
    if (kt + 1 < TK) {
      issue();          // stage kt+1; stays in flight
      waitcnt_vm<4>();  // drain stage kt only
    } else {
      waitcnt_vm<0>();
    }
    __builtin_amdgcn_s_barrier();
    const _Float16* sb = sm + cur * SSTR;
    half8 af[4], bf[4];
#pragma unroll
    for (int t = 0; t < 4; t++) af[t] = *(const half8*)(sb + aoff[t]);
#pragma unroll
    for (int t = 0; t < 4; t++) bf[t] = *(const half8*)(sb + boff[t]);
#pragma unroll
    for (int i = 0; i < 4; i++)
#pragma unroll
      for (int j = 0; j < 4; j++)
        acc[i][j] = __builtin_amdgcn_mfma_f32_16x16x32_f16(af[i], bf[j], acc[i][j], 0, 0, 0);
    cur = (cur == 2) ? 0 : cur + 1;
  }

  // epilogue: D layout col=lane&15, row=(lane>>4)*4+r
  _Float16* Dp = khalf ? D1 : D0;
  int cq = (lane >> 4) * 4, cc = lane & 15;
#pragma unroll
  for (int i = 0; i < 4; i++) {
#pragma unroll
    for (int r = 0; r < 4; r++) {
      int m = wm + i * 16 + cq + r;
      if (m0 + m < cnt) {
        if (IS_UP) {
          float w = gw[off + m0 + m];
          _Float16* hrow = Hout + (size_t)(off + m0 + m) * NDIM + n0;
#pragma unroll
          for (int j = 0; j < 4; j++) {
            float v = acc[i][j][r];
            float gl = 0.5f * v * (1.f + erff(v * 0.70710678118f));
            hrow[wn + j * 16 + cc] = (_Float16)(gl * w);
          }
        } else {
          _Float16* orow = Dp + (size_t)(off + m0 + m) * NDIM + n0;
#pragma unroll
          for (int j = 0; j < 4; j++) orow[wn + j * 16 + cc] = (_Float16)acc[i][j][r];
        }
      }
    }
  }
}

// out[token] = sum over {2 slots} x {2 k-halves} of fp16 partials
__global__ __launch_bounds__(256) void combine_kernel(
    const _Float16* __restrict__ D0, const _Float16* __restrict__ D1,
    const int* __restrict__ srow, float* __restrict__ out) {
  int n = blockIdx.x;
  int t = threadIdx.x;
  int r0 = srow[n * 2], r1 = srow[n * 2 + 1];
  half4f a0 = *(const half4f*)(D0 + (size_t)r0 * HD + t * 4);
  half4f a1 = *(const half4f*)(D1 + (size_t)r0 * HD + t * 4);
  half4f b0 = *(const half4f*)(D0 + (size_t)r1 * HD + t * 4);
  half4f b1 = *(const half4f*)(D1 + (size_t)r1 * HD + t * 4);
  float4 c;
  c.x = (float)a0[0] + (float)a1[0] + (float)b0[0] + (float)b1[0];
  c.y = (float)a0[1] + (float)a1[1] + (float)b0[1] + (float)b1[1];
  c.z = (float)a0[2] + (float)a1[2] + (float)b0[2] + (float)b1[2];
  c.w = (float)a0[3] + (float)a1[3] + (float)b0[3] + (float)b1[3];
  *(float4*)(out + (size_t)n * HD + t * 4) = c;
}

// ---------------- launch ----------------
extern "C" void kernel_launch(void* const* d_in, const int* in_sizes, int n_in,
                              void* d_out, int out_size, void* d_ws, size_t ws_size,
                              hipStream_t stream) {
  const float* x = (const float*)d_in[0];     // [4096,1024]
  const float* rw = (const float*)d_in[1];    // [8,1024]
  const float* up_w = (const float*)d_in[2];  // [8,1024,2048]
  const float* dn_w = (const float*)d_in[3];  // [8,2048,1024]
  float* out = (float*)d_out;                 // [4096*1024] ++ [1]

  char* ws = (char*)d_ws;
  _Float16* Xh   = (_Float16*)(ws + 0);          // 8 MB  (dead after up-GEMM)
  _Float16* Wut  = (_Float16*)(ws + 8388608);    // 32 MB (dead after up-GEMM)
  _Float16* D0   = (_Float16*)(ws + 0);          // 16 MB ALIAS over Xh/Wut
  _Float16* D1   = (_Float16*)(ws + 16777216);   // 16 MB ALIAS over Wut
  _Float16* Wdt  = (_Float16*)(ws + 41943040);   // 32 MB [8][1024][2048]
  _Float16* Hbuf = (_Float16*)(ws + 75497472);   // 32 MB [8192][2048]
  char* tail = ws + 109051904;
  int*   gtok   = (int*)(tail + 0);        // 32 KB
  float* gw     = (float*)(tail + 32768);  // 32 KB
  int*   sel_e  = (int*)(tail + 65536);    // 32 KB
  float* sel_w  = (float*)(tail + 98304);  // 32 KB
  int*   srow   = (int*)(tail + 131072);   // 32 KB
  float* probs  = (float*)(tail + 163840); // 128 KB
  int*   counts = (int*)(tail + 294912);
  int*   offs   = (int*)(tail + 294944);
  int*   cursor = (int*)(tail + 294976);

  cvt_x_kernel<<<(NT * HD / 8) / 256, 256, 0, stream>>>(x, Xh);
  transpose_cvt<<<dim3(HD / 32, FD / 32, NE), dim3(32, 8), 0, stream>>>(up_w, Wut, HD, FD);
  transpose_cvt<<<dim3(FD / 32, HD / 32, NE), dim3(32, 8), 0, stream>>>(dn_w, Wdt, FD, HD);
  router_probs_kernel<<<NT / 4, 256, 0, stream>>>(x, rw, probs, sel_e, sel_w);
  router_reduce_kernel<<<1, 1024, 0, stream>>>(probs, sel_e, counts, offs, cursor,
                                               out + (size_t)NT * HD);
  build_gather<<<NSLOT / 256, 256, 0, stream>>>(sel_e, sel_w, offs, cursor, gtok, gw, srow);

  // up: A=[gathered Xh] (K=1024), B=Wut (N=2048) -> Hbuf (fp16, gelu*w applied)
  moe_gemm4<HD, HD, FD, true, false><<<dim3(NSLOT / 128, FD / 128, NE), 256, 0, stream>>>(
      Xh, Wut, counts, offs, gtok, gw, Hbuf, nullptr, nullptr);
  // down: A=Hbuf (K=2048 split into 2x1024), B=Wdt -> fp16 partials D0/D1
  moe_gemm4<HD, FD, HD, false, true><<<dim3(NSLOT / 128, HD / 128, NE * 2), 256, 0, stream>>>(
      Hbuf, Wdt, counts, offs, gtok, gw, nullptr, D0, D1);
  combine_kernel<<<NT, 256, 0, stream>>>(D0, D1, srow, out);
}

// Round 6
// 316.863 us; speedup vs baseline: 2.1894x; 2.1894x over previous
//
#include <hip/hip_runtime.h>
#include <math.h>

#define NE 8
#define HD 1024
#define FD 2048
#define NT 4096
#define NSLOT (NT * 2)

typedef __attribute__((ext_vector_type(8))) _Float16 half8;
typedef __attribute__((ext_vector_type(4))) float floatx4;

// async global->LDS, 16B per lane. LDS dest is wave-uniform base + lane*16.
__device__ __forceinline__ void gload_lds(const _Float16* g, _Float16* l) {
  __builtin_amdgcn_global_load_lds(
      (const __attribute__((address_space(1))) unsigned int*)g,
      (__attribute__((address_space(3))) unsigned int*)l, 16, 0, 0);
}

// ---------------- conversions ----------------
__global__ void cvt_x_kernel(const float* __restrict__ x, _Float16* __restrict__ xh) {
  size_t i = (size_t)(blockIdx.x * 256 + threadIdx.x) * 8;
  float4 f0 = *(const float4*)(x + i);
  float4 f1 = *(const float4*)(x + i + 4);
  union { _Float16 h[8]; uint4 v; } u;
  u.h[0] = (_Float16)f0.x; u.h[1] = (_Float16)f0.y;
  u.h[2] = (_Float16)f0.z; u.h[3] = (_Float16)f0.w;
  u.h[4] = (_Float16)f1.x; u.h[5] = (_Float16)f1.y;
  u.h[6] = (_Float16)f1.z; u.h[7] = (_Float16)f1.w;
  *(uint4*)(xh + i) = u.v;
}

// in: [E][R][C] fp32 -> out: [E][C][R] fp16. Write phase: 8B (4 halfs) per lane.
__global__ void transpose_cvt(const float* __restrict__ in, _Float16* __restrict__ outp,
                              int R, int C) {
  __shared__ float t[32][33];
  int e = blockIdx.z;
  int r0 = blockIdx.x * 32, c0 = blockIdx.y * 32;
  int tx = threadIdx.x, ty = threadIdx.y;  // (32,8)
  const float* src = in + (size_t)e * R * C;
#pragma unroll
  for (int i = 0; i < 4; i++)
    t[ty + 8 * i][tx] = src[(size_t)(r0 + ty + 8 * i) * C + c0 + tx];
  __syncthreads();
  _Float16* dst = outp + (size_t)e * R * C;
  int tid = ty * 32 + tx;
  int cl = tid >> 3, rq = tid & 7;  // col 0..31, r-quad 0..7
  union { _Float16 h[4]; uint2 v; } o;
#pragma unroll
  for (int k = 0; k < 4; k++) o.h[k] = (_Float16)t[rq * 4 + k][cl];
  *(uint2*)(dst + (size_t)(c0 + cl) * R + r0 + rq * 4) = o.v;
}

// ---------------- router ----------------
__global__ __launch_bounds__(256) void router_probs_kernel(
    const float* __restrict__ x, const float* __restrict__ rw,
    float* __restrict__ probs, int* __restrict__ sel_e, float* __restrict__ sel_w) {
  int n = blockIdx.x * 4 + (threadIdx.x >> 6);
  int lane = threadIdx.x & 63;
  const float* xr = x + (size_t)n * HD;
  float xv[16];
#pragma unroll
  for (int t = 0; t < 16; t++) xv[t] = xr[lane + 64 * t];
  float logits[NE];
#pragma unroll
  for (int e = 0; e < NE; e++) {
    const float* w = rw + (size_t)e * HD;
    float acc = 0.f;
#pragma unroll
    for (int t = 0; t < 16; t++) acc += xv[t] * w[lane + 64 * t];
    for (int off = 32; off > 0; off >>= 1) acc += __shfl_down(acc, off);
    logits[e] = acc;
  }
  if (lane == 0) {
    float mx = logits[0];
#pragma unroll
    for (int e = 1; e < NE; e++) mx = fmaxf(mx, logits[e]);
    float p[NE]; float s = 0.f;
#pragma unroll
    for (int e = 0; e < NE; e++) { p[e] = expf(logits[e] - mx); s += p[e]; }
    float inv = 1.f / s;
#pragma unroll
    for (int e = 0; e < NE; e++) { p[e] *= inv; probs[n * NE + e] = p[e]; }
    int i1 = 0;
#pragma unroll
    for (int e = 1; e < NE; e++) if (p[e] > p[i1]) i1 = e;
    int i2 = -1; float p2 = -1.f;
#pragma unroll
    for (int e = 0; e < NE; e++) {
      if (e == i1) continue;
      if (p[e] > p2) { p2 = p[e]; i2 = e; }
    }
    float wn = 1.f / (p[i1] + p[i2]);
    sel_e[n * 2 + 0] = i1; sel_w[n * 2 + 0] = p[i1] * wn;
    sel_e[n * 2 + 1] = i2; sel_w[n * 2 + 1] = p[i2] * wn;
  }
}

__global__ __launch_bounds__(1024) void router_reduce_kernel(
    const float* __restrict__ probs, const int* __restrict__ sel_e,
    int* __restrict__ counts, int* __restrict__ offs, int* __restrict__ cursor,
    float* __restrict__ aux_out) {
  int t = threadIdx.x;
  int lane = t & 63, wave = t >> 6;
  float ps[NE];
  int cn[NE];
#pragma unroll
  for (int e = 0; e < NE; e++) { ps[e] = 0.f; cn[e] = 0; }
  for (int r = t; r < NT; r += 1024) {
    const float* pr = probs + (size_t)r * NE;
#pragma unroll
    for (int e = 0; e < NE; e++) ps[e] += pr[e];
  }
  for (int i = t; i < NSLOT; i += 1024) {
    int e = sel_e[i];
#pragma unroll
    for (int j = 0; j < NE; j++) cn[j] += (e == j) ? 1 : 0;
  }
  for (int off = 32; off > 0; off >>= 1) {
#pragma unroll
    for (int e = 0; e < NE; e++) {
      ps[e] += __shfl_down(ps[e], off);
      cn[e] += __shfl_down(cn[e], off);
    }
  }
  __shared__ float sps[16][NE];
  __shared__ int scn[16][NE];
  if (lane == 0) {
#pragma unroll
    for (int e = 0; e < NE; e++) { sps[wave][e] = ps[e]; scn[wave][e] = cn[e]; }
  }
  __syncthreads();
  if (t == 0) {
    float tot_p[NE]; int tot_c[NE];
#pragma unroll
    for (int e = 0; e < NE; e++) { tot_p[e] = 0.f; tot_c[e] = 0; }
    for (int w = 0; w < 16; w++)
#pragma unroll
      for (int e = 0; e < NE; e++) { tot_p[e] += sps[w][e]; tot_c[e] += scn[w][e]; }
    int o = 0;
    float aux = 0.f;
    for (int e = 0; e < NE; e++) {
      counts[e] = tot_c[e];
      offs[e] = o; o += tot_c[e];
      cursor[e] = 0;
      aux += ((float)tot_c[e] / (float)NSLOT) * (tot_p[e] / (float)NT);
    }
    aux_out[0] = (float)NE * aux;
  }
}

__global__ __launch_bounds__(256) void build_gather(
    const int* __restrict__ sel_e, const float* __restrict__ sel_w,
    const int* __restrict__ offs, int* __restrict__ cursor,
    int* __restrict__ gtok, float* __restrict__ gw, int* __restrict__ srow) {
  __shared__ int lh[NE], lbase[NE];
  int t = threadIdx.x;
  int i = blockIdx.x * 256 + t;
  if (t < NE) lh[t] = 0;
  __syncthreads();
  int e = sel_e[i];
  int lrank = atomicAdd(&lh[e], 1);
  __syncthreads();
  if (t < NE) lbase[t] = atomicAdd(&cursor[t], lh[t]);
  __syncthreads();
  int row = offs[e] + lbase[e] + lrank;
  gtok[row] = i >> 1;
  gw[row] = sel_w[i];
  srow[i] = row;
}

// ---------------- grouped GEMM (R3 core, XCD-pinned grid) ----------------
// BM=BN=128, BK=64, 256 thr = 4 waves. global_load_lds width-16 staging,
// XOR-swizzled 128B LDS rows (0 bank conflicts, verified R3).
// GRID: (x=expert, y=m-block, z=n-block). gridDim.x == 8 == #XCDs, so with
// round-robin workgroup dispatch all blocks of expert e land on XCD e ->
// per-XCD L2 working set = one expert's A (2-4 MB) + streaming 256KB B-blocks.
// m varies fastest => concurrent blocks share the same B n-block.
template <int KDIM, int NDIM, bool IS_UP>
__global__ __launch_bounds__(256, 3) void moe_gemm2(
    const _Float16* __restrict__ Abase, const _Float16* __restrict__ Bt,
    const int* __restrict__ counts, const int* __restrict__ offs,
    const int* __restrict__ gtok, const float* __restrict__ gw,
    _Float16* __restrict__ Hout, float* __restrict__ Dout) {
  int e = blockIdx.x;
  int cnt = counts[e];
  int m0 = blockIdx.y * 128;
  if (m0 >= cnt) return;
  int n0 = blockIdx.z * 128;
  int off = offs[e];

  __shared__ __align__(16) _Float16 As[128 * 64];  // 16 KB
  __shared__ __align__(16) _Float16 Bs[128 * 64];  // 16 KB

  int tid = threadIdx.x;
  int lane = tid & 63, wave = tid >> 6;
  int wm = (wave >> 1) * 64, wn = (wave & 1) * 64;

  // staging: wave stages rows [wave*32, wave*32+32), 8 rows per dma insn
  int srow8 = lane >> 3;            // row within 8-row group
  int chunk = (lane & 7) ^ srow8;   // logical 16B chunk this lane fetches
  const _Float16* ga[4];
  const _Float16* gb[4];
  _Float16* lA[4];
  _Float16* lB[4];
#pragma unroll
  for (int j = 0; j < 4; j++) {
    int r = wave * 32 + j * 8 + srow8;  // 0..127 tile row
    int am = m0 + r;
    if (am > cnt - 1) am = cnt - 1;  // clamp tail (masked at epilogue)
    if (IS_UP) {
      ga[j] = Abase + (size_t)gtok[off + am] * KDIM + chunk * 8;
    } else {
      ga[j] = Abase + (size_t)(off + am) * KDIM + chunk * 8;
    }
    gb[j] = Bt + ((size_t)e * NDIM + n0 + r) * KDIM + chunk * 8;
    lA[j] = As + (wave * 32 + j * 8) * 64;
    lB[j] = Bs + (wave * 32 + j * 8) * 64;
  }

  floatx4 acc[4][4];
#pragma unroll
  for (int i = 0; i < 4; i++)
#pragma unroll
    for (int j = 0; j < 4; j++) acc[i][j] = (floatx4){0.f, 0.f, 0.f, 0.f};

  int fr = lane & 15, g = lane >> 4;
  int sw0 = ((g) ^ (fr & 7)) * 8;      // substep 0: logical chunk g
  int sw1 = ((4 + g) ^ (fr & 7)) * 8;  // substep 1: logical chunk 4+g

  for (int kt = 0; kt < KDIM / 64; kt++) {
    __syncthreads();  // previous tile's reads done before overwrite
#pragma unroll
    for (int j = 0; j < 4; j++) gload_lds(ga[j], lA[j]);
#pragma unroll
    for (int j = 0; j < 4; j++) gload_lds(gb[j], lB[j]);
#pragma unroll
    for (int j = 0; j < 4; j++) { ga[j] += 64; gb[j] += 64; }
    __syncthreads();  // drains vmcnt -> tiles visible

    half8 af[4], bfv[4];
#pragma unroll
    for (int t = 0; t < 4; t++) {
      af[t] = *(const half8*)(As + (wm + t * 16 + fr) * 64 + sw0);
      bfv[t] = *(const half8*)(Bs + (wn + t * 16 + fr) * 64 + sw0);
    }
#pragma unroll
    for (int i = 0; i < 4; i++)
#pragma unroll
      for (int j = 0; j < 4; j++)
        acc[i][j] = __builtin_amdgcn_mfma_f32_16x16x32_f16(af[i], bfv[j], acc[i][j], 0, 0, 0);
#pragma unroll
    for (int t = 0; t < 4; t++) {
      af[t] = *(const half8*)(As + (wm + t * 16 + fr) * 64 + sw1);
      bfv[t] = *(const half8*)(Bs + (wn + t * 16 + fr) * 64 + sw1);
    }
#pragma unroll
    for (int i = 0; i < 4; i++)
#pragma unroll
      for (int j = 0; j < 4; j++)
        acc[i][j] = __builtin_amdgcn_mfma_f32_16x16x32_f16(af[i], bfv[j], acc[i][j], 0, 0, 0);
  }

  // epilogue: D layout col=lane&15, row=(lane>>4)*4+r
  int cq = (lane >> 4) * 4, cc = lane & 15;
#pragma unroll
  for (int i = 0; i < 4; i++) {
#pragma unroll
    for (int r = 0; r < 4; r++) {
      int m = wm + i * 16 + cq + r;
      if (m0 + m < cnt) {
        if (IS_UP) {
          float w = gw[off + m0 + m];
          _Float16* hrow = Hout + (size_t)(off + m0 + m) * NDIM + n0;
#pragma unroll
          for (int j = 0; j < 4; j++) {
            float v = acc[i][j][r];
            float gl = 0.5f * v * (1.f + erff(v * 0.70710678118f));
            hrow[wn + j * 16 + cc] = (_Float16)(gl * w);
          }
        } else {
          float* orow = Dout + (size_t)(off + m0 + m) * NDIM + n0;
#pragma unroll
          for (int j = 0; j < 4; j++) orow[wn + j * 16 + cc] = acc[i][j][r];
        }
      }
    }
  }
}

__global__ __launch_bounds__(256) void combine_kernel(
    const float* __restrict__ Dout, const int* __restrict__ srow,
    float* __restrict__ out) {
  int n = blockIdx.x;
  int t = threadIdx.x;
  int r0 = srow[n * 2], r1 = srow[n * 2 + 1];
  float4 a = *(const float4*)(Dout + (size_t)r0 * HD + t * 4);
  float4 b = *(const float4*)(Dout + (size_t)r1 * HD + t * 4);
  float4 c; c.x = a.x + b.x; c.y = a.y + b.y; c.z = a.z + b.z; c.w = a.w + b.w;
  *(float4*)(out + (size_t)n * HD + t * 4) = c;
}

// ---------------- launch ----------------
extern "C" void kernel_launch(void* const* d_in, const int* in_sizes, int n_in,
                              void* d_out, int out_size, void* d_ws, size_t ws_size,
                              hipStream_t stream) {
  const float* x = (const float*)d_in[0];     // [4096,1024]
  const float* rw = (const float*)d_in[1];    // [8,1024]
  const float* up_w = (const float*)d_in[2];  // [8,1024,2048]
  const float* dn_w = (const float*)d_in[3];  // [8,2048,1024]
  float* out = (float*)d_out;                 // [4096*1024] ++ [1]

  char* ws = (char*)d_ws;
  _Float16* Xh   = (_Float16*)(ws + 0);          // 8 MB  (dead after up-GEMM)
  _Float16* Wut  = (_Float16*)(ws + 8388608);    // 32 MB (dead after up-GEMM)
  float*    Dout = (float*)(ws + 0);             // 32 MB ALIAS over Xh+Wut
  _Float16* Wdt  = (_Float16*)(ws + 41943040);   // 32 MB [8][1024][2048]
  _Float16* Hbuf = (_Float16*)(ws + 75497472);   // 32 MB [8192][2048]
  char* tail = ws + 109051904;
  int*   gtok   = (int*)(tail + 0);        // 32 KB
  float* gw     = (float*)(tail + 32768);  // 32 KB
  int*   sel_e  = (int*)(tail + 65536);    // 32 KB
  float* sel_w  = (float*)(tail + 98304);  // 32 KB
  int*   srow   = (int*)(tail + 131072);   // 32 KB
  float* probs  = (float*)(tail + 163840); // 128 KB
  int*   counts = (int*)(tail + 294912);
  int*   offs   = (int*)(tail + 294944);
  int*   cursor = (int*)(tail + 294976);

  cvt_x_kernel<<<(NT * HD / 8) / 256, 256, 0, stream>>>(x, Xh);
  transpose_cvt<<<dim3(HD / 32, FD / 32, NE), dim3(32, 8), 0, stream>>>(up_w, Wut, HD, FD);
  transpose_cvt<<<dim3(FD / 32, HD / 32, NE), dim3(32, 8), 0, stream>>>(dn_w, Wdt, FD, HD);
  router_probs_kernel<<<NT / 4, 256, 0, stream>>>(x, rw, probs, sel_e, sel_w);
  router_reduce_kernel<<<1, 1024, 0, stream>>>(probs, sel_e, counts, offs, cursor,
                                               out + (size_t)NT * HD);
  build_gather<<<NSLOT / 256, 256, 0, stream>>>(sel_e, sel_w, offs, cursor, gtok, gw, srow);

  // up: A=[gathered Xh] (K=1024), B=Wut (N=2048) -> Hbuf. Grid (e, m, n): XCD-pinned.
  moe_gemm2<HD, FD, true><<<dim3(NE, 32, FD / 128), 256, 0, stream>>>(
      Xh, Wut, counts, offs, gtok, gw, Hbuf, nullptr);
  // down: A=Hbuf (K=2048), B=Wdt (N=1024) -> Dout fp32 per slot. XCD-pinned.
  moe_gemm2<FD, HD, false><<<dim3(NE, 32, HD / 128), 256, 0, stream>>>(
      Hbuf, Wdt, counts, offs, gtok, gw, nullptr, Dout);
  combine_kernel<<<NT, 256, 0, stream>>>(Dout, srow, out);
}